// Round 5
// baseline (559.804 us; speedup 1.0000x reference)
//
#include <hip/hip_runtime.h>
#include <stdint.h>

#define B_   8
#define S_   2048
#define D_   1024
#define E_   2048
#define SD_  128
#define M_   (B_ * S_)        // 16384
#define NUV  (2 * E_ + SD_)   // 4224
#define NUV2 4352             // padded region kept for layout stability

typedef __attribute__((ext_vector_type(8))) short short8;
typedef __attribute__((ext_vector_type(4))) float floatx4;

typedef __attribute__((address_space(1))) void as1_void;
typedef __attribute__((address_space(3))) void as3_void;

__device__ __forceinline__ ushort f2bf(float f) {
    uint32_t u = __float_as_uint(f);
    uint32_t r = (u + 0x7fffu + ((u >> 16) & 1u)) >> 16;  // RNE
    return (ushort)r;
}
__device__ __forceinline__ float bf2f(ushort h) {
    return __uint_as_float(((uint32_t)h) << 16);
}
__device__ __forceinline__ float silu(float z) {
    return z * __builtin_amdgcn_rcpf(1.0f + __expf(-z));
}
__device__ __forceinline__ void gld_lds16(const ushort* g, ushort* l) {
    __builtin_amdgcn_global_load_lds((const as1_void*)g, (as3_void*)l, 16, 0, 0);
}

// ===========================================================================
// 128-tile machinery (proven 875 TF on gemm1 shape; 3 blocks/CU overlap)
// ===========================================================================

// Two-level supertile swizzle: 8 m-tiles x 4 n-tiles per supertile (32 blocks).
__device__ __forceinline__ void tile_swizzle(int& mt, int& nt) {
    const int gx  = gridDim.x;                 // n-tiles
    const int lin = blockIdx.y * gx + blockIdx.x;
    const int bandSz = gx * 8;
    const int band = lin / bandSz;
    const int rem  = lin - band * bandSz;
    const int full = gx >> 2;                  // # full 4-wide n-chunks
    const int sc   = rem >> 5;                 // /32
    if (sc < full) {
        const int r2 = rem & 31;
        mt = band * 8 + (r2 & 7);
        nt = sc * 4 + (r2 >> 3);
    } else {                                   // remainder chunk (gx%4 cols)
        const int r3 = rem - full * 32;
        mt = band * 8 + (r3 & 7);
        nt = full * 4 + (r3 >> 3);
    }
}

// C[128x128] tile of A[M,K] @ B[N,K]^T. 4 waves 2x2, wave tile 64x64 =
// 4x4 MFMA 16x16x32. BK=64, 32KB LDS. 2-barrier K-loop, global_load_lds
// width=16, XOR-swizzled LDS (key=row&7) -> 0 bank conflicts.
__device__ __forceinline__ void gemm_core(
    const ushort* __restrict__ A, const ushort* __restrict__ B,
    int lda, int ldb, int K, int m0, int n0,
    ushort* ldsA, ushort* ldsB, floatx4 acc[4][4])
{
    const int t    = threadIdx.x;
    const int lane = t & 63;
    const int l15  = lane & 15;
    const int quad = lane >> 4;
    const int wave = t >> 6;
    const int wm   = (wave >> 1) * 64;
    const int wn   = (wave & 1) * 64;
    const int key  = l15 & 7;

    const ushort* gA[4]; const ushort* gB[4];
    ushort* lA[4]; ushort* lB[4];
    #pragma unroll
    for (int i = 0; i < 4; ++i) {
        const int c   = t + i * 256;
        const int row = c >> 3;
        const int gkc = ((c & 7) ^ (row & 7)) * 8;
        gA[i] = A + (size_t)(m0 + row) * lda + gkc;
        gB[i] = B + (size_t)(n0 + row) * ldb + gkc;
        lA[i] = ldsA + c * 8;
        lB[i] = ldsB + c * 8;
    }

    for (int kk = 0; kk < K; kk += 64) {
        __syncthreads();
        #pragma unroll
        for (int i = 0; i < 4; ++i) gld_lds16(gA[i] + kk, lA[i]);
        #pragma unroll
        for (int i = 0; i < 4; ++i) gld_lds16(gB[i] + kk, lB[i]);
        __syncthreads();  // vmcnt(0) drain -> staged data visible

        #pragma unroll
        for (int s = 0; s < 2; ++s) {
            const int koff = ((s * 4 + quad) ^ key) * 8;
            short8 af[4], bfr[4];
            #pragma unroll
            for (int mi = 0; mi < 4; ++mi)
                af[mi] = *(const short8*)(ldsA + (wm + mi * 16 + l15) * 64 + koff);
            #pragma unroll
            for (int ni = 0; ni < 4; ++ni)
                bfr[ni] = *(const short8*)(ldsB + (wn + ni * 16 + l15) * 64 + koff);
            #pragma unroll
            for (int mi = 0; mi < 4; ++mi)
                #pragma unroll
                for (int ni = 0; ni < 4; ++ni)
                    acc[mi][ni] = __builtin_amdgcn_mfma_f32_16x16x32_bf16(
                        af[mi], bfr[ni], acc[mi][ni], 0, 0, 0);
        }
    }
}

#define EPI_INDICES \
    const int t = threadIdx.x; \
    const int lane = t & 63, l15 = lane & 15, quad = lane >> 4; \
    const int wave = t >> 6, wm = (wave >> 1) * 64, wn = (wave & 1) * 64; \
    (void)t;

#define ZERO_ACC \
    floatx4 acc[4][4]; \
    _Pragma("unroll") \
    for (int i = 0; i < 4; ++i) \
        _Pragma("unroll") \
        for (int j = 0; j < 4; ++j) \
            _Pragma("unroll") \
            for (int r = 0; r < 4; ++r) acc[i][j][r] = 0.0f;

// ===========================================================================
// 256-tile 4-phase machinery (v3: PHB A-fragments register-prefetched in PHA
// -> PHB has zero ds_reads / zero lgkm wait on its critical path)
// ===========================================================================

__device__ __forceinline__ void tile_swizzle4(int& mt, int& nt) {
    const int gx  = gridDim.x;                 // n-tiles
    const int lin = blockIdx.y * gx + blockIdx.x;
    const int bandSz = gx * 4;
    const int band = lin / bandSz;
    const int rem  = lin - band * bandSz;
    const int full = gx >> 2;
    const int sc   = rem >> 4;
    if (sc < full) {
        const int r2 = rem & 15;
        mt = band * 4 + (r2 & 3);
        nt = sc * 4 + (r2 >> 2);
    } else {
        const int r3 = rem - full * 16;
        mt = band * 4 + (r3 & 3);
        nt = full * 4 + (r3 >> 2);
    }
}

#define STAGE_A(bufn, h, kk) { \
    gld_lds16(gA0 + (size_t)(h) * a128 + (kk), LA##bufn + (h) * 8192 + t * 8); \
    gld_lds16(gA1 + (size_t)(h) * a128 + (kk), LA##bufn + (h) * 8192 + t * 8 + 4096); }
#define STAGE_B(bufn, h, kk) { \
    gld_lds16(gB0 + (size_t)(h) * b128 + (kk), LB##bufn + (h) * 8192 + t * 8); \
    gld_lds16(gB1 + (size_t)(h) * b128 + (kk), LB##bufn + (h) * 8192 + t * 8 + 4096); }

// PHA: ds_read af(mq=0) + PREFETCH afB(mq=1) + all bf; 32 MFMA on quadrants
// (0,*). Validity of LA{buf}h1 at read time is covered by the preceding
// counted-vmcnt (the retired-oldest loads are exactly that half-tile) and no
// wave writes that region until after this phase's trailing barrier.
#define PHA(bufn, STAGES) { \
    short8 af_[4][2]; \
    { const ushort* pa_  = LA##bufn + aoff; \
      const ushort* pa1_ = LA##bufn + 8192 + aoff; \
      const ushort* pb_  = LB##bufn + boff; \
      _Pragma("unroll") \
      for (int mi_ = 0; mi_ < 4; ++mi_) { \
          af_[mi_][0] = *(const short8*)(pa_ + mi_ * 1024 + koff0); \
          af_[mi_][1] = *(const short8*)(pa_ + mi_ * 1024 + koff1); } \
      _Pragma("unroll") \
      for (int mi_ = 0; mi_ < 4; ++mi_) { \
          afB[mi_][0] = *(const short8*)(pa1_ + mi_ * 1024 + koff0); \
          afB[mi_][1] = *(const short8*)(pa1_ + mi_ * 1024 + koff1); } \
      _Pragma("unroll") \
      for (int nq_ = 0; nq_ < 2; ++nq_) \
      _Pragma("unroll") \
      for (int ni_ = 0; ni_ < 2; ++ni_) { \
          bfv[nq_][ni_][0] = *(const short8*)(pb_ + nq_ * 8192 + ni_ * 1024 + koff0); \
          bfv[nq_][ni_][1] = *(const short8*)(pb_ + nq_ * 8192 + ni_ * 1024 + koff1); } } \
    STAGES \
    __builtin_amdgcn_s_barrier(); \
    asm volatile("s_waitcnt lgkmcnt(0)" ::: "memory"); \
    __builtin_amdgcn_sched_barrier(0); \
    __builtin_amdgcn_s_setprio(1); \
    _Pragma("unroll") \
    for (int nq_ = 0; nq_ < 2; ++nq_) \
    _Pragma("unroll") \
    for (int mi_ = 0; mi_ < 4; ++mi_) \
    _Pragma("unroll") \
    for (int ni_ = 0; ni_ < 2; ++ni_) { \
        acc[0][nq_][mi_][ni_] = __builtin_amdgcn_mfma_f32_16x16x32_bf16( \
            af_[mi_][0], bfv[nq_][ni_][0], acc[0][nq_][mi_][ni_], 0, 0, 0); \
        acc[0][nq_][mi_][ni_] = __builtin_amdgcn_mfma_f32_16x16x32_bf16( \
            af_[mi_][1], bfv[nq_][ni_][1], acc[0][nq_][mi_][ni_], 0, 0, 0); } \
    __builtin_amdgcn_s_setprio(0); \
    __builtin_amdgcn_s_barrier(); }

// PHB: pure-register MFMA (afB/bfv from PHA), no ds_reads, no lgkm wait.
#define PHB(STAGES, WAITC) { \
    STAGES \
    __builtin_amdgcn_s_barrier(); \
    __builtin_amdgcn_s_setprio(1); \
    _Pragma("unroll") \
    for (int nq_ = 0; nq_ < 2; ++nq_) \
    _Pragma("unroll") \
    for (int mi_ = 0; mi_ < 4; ++mi_) \
    _Pragma("unroll") \
    for (int ni_ = 0; ni_ < 2; ++ni_) { \
        acc[1][nq_][mi_][ni_] = __builtin_amdgcn_mfma_f32_16x16x32_bf16( \
            afB[mi_][0], bfv[nq_][ni_][0], acc[1][nq_][mi_][ni_], 0, 0, 0); \
        acc[1][nq_][mi_][ni_] = __builtin_amdgcn_mfma_f32_16x16x32_bf16( \
            afB[mi_][1], bfv[nq_][ni_][1], acc[1][nq_][mi_][ni_], 0, 0, 0); } \
    __builtin_amdgcn_s_setprio(0); \
    WAITC \
    __builtin_amdgcn_s_barrier(); }

__device__ __forceinline__ void gemm256(
    const ushort* __restrict__ A, const ushort* __restrict__ B,
    int lda, int ldb, int K, int m0, int n0,
    ushort* lds, floatx4 (&acc)[2][2][4][2])
{
    const int t    = threadIdx.x;
    const int lane = t & 63;
    const int l15  = lane & 15;
    const int quad = lane >> 4;
    const int w    = t >> 6;
    const int wr   = w >> 2;
    const int wc   = w & 3;
    const int key  = l15 & 7;
    const int aoff  = (wr * 64 + l15) * 64;
    const int boff  = (wc * 32 + l15) * 64;
    const int koff0 = (quad ^ key) * 8;
    const int koff1 = ((quad + 4) ^ key) * 8;

    ushort* const LA0 = lds;
    ushort* const LA1 = lds + 16384;
    ushort* const LB0 = lds + 32768;
    ushort* const LB1 = lds + 49152;

    const int r0 = t >> 3;
    const int k0 = ((t & 7) ^ (r0 & 7)) * 8;
    const ushort* gA0 = A + (size_t)(m0 + r0) * lda + k0;
    const ushort* gA1 = gA0 + (size_t)64 * lda;
    const ushort* gB0 = B + (size_t)(n0 + r0) * ldb + k0;
    const ushort* gB1 = gB0 + (size_t)64 * ldb;
    const size_t a128 = (size_t)128 * lda;
    const size_t b128 = (size_t)128 * ldb;

    short8 bfv[2][2][2];   // [nq][ni][kh], loaded in PHA, reused in PHB
    short8 afB[4][2];      // A(mq=1) fragments, prefetched in PHA for PHB

    STAGE_A(0, 0, 0) STAGE_A(0, 1, 0) STAGE_B(0, 0, 0) STAGE_B(0, 1, 0)
    STAGE_A(1, 0, 64) STAGE_B(1, 0, 64) STAGE_B(1, 1, 64)
    asm volatile("s_waitcnt vmcnt(6)" ::: "memory");
    __builtin_amdgcn_s_barrier();

    const int nIter = K >> 7;                          // K-tile pairs
    #pragma unroll 1
    for (int i = 0; i < nIter; ++i) {
        const bool lastI = (i == nIter - 1);
        const int kb = i * 128;
        PHA(0, STAGE_A(1, 1, kb + 64))
        PHB(if (!lastI) { STAGE_A(0, 0, kb + 128) STAGE_B(0, 0, kb + 128) STAGE_B(0, 1, kb + 128) },
            if (!lastI) { asm volatile("s_waitcnt vmcnt(6)" ::: "memory"); }
            else        { asm volatile("s_waitcnt vmcnt(0)" ::: "memory"); })
        PHA(1, if (!lastI) { STAGE_A(0, 1, kb + 128) })
        PHB(if (!lastI) { STAGE_A(1, 0, kb + 192) STAGE_B(1, 0, kb + 192) STAGE_B(1, 1, kb + 192) },
            if (!lastI) { asm volatile("s_waitcnt vmcnt(6)" ::: "memory"); })
    }
}

#define ZERO_ACC256 \
    floatx4 acc[2][2][4][2]; \
    _Pragma("unroll") for (int zq_ = 0; zq_ < 2; ++zq_) \
    _Pragma("unroll") for (int zn_ = 0; zn_ < 2; ++zn_) \
    _Pragma("unroll") for (int zm_ = 0; zm_ < 4; ++zm_) \
    _Pragma("unroll") for (int zl_ = 0; zl_ < 2; ++zl_) \
    _Pragma("unroll") for (int zr_ = 0; zr_ < 4; ++zr_) \
        acc[zq_][zn_][zm_][zl_][zr_] = 0.0f;

#define EPI256 \
    const int t = threadIdx.x; \
    const int lane = t & 63, l15 = lane & 15, quad = lane >> 4; \
    const int w = t >> 6, wr = w >> 2, wc = w & 3; \
    (void)t; (void)lane;

// ---------------------------------------------------------------------------
// prep kernels
// ---------------------------------------------------------------------------
__global__ __launch_bounds__(256) void k_cvt(const float* __restrict__ src,
                                             ushort* __restrict__ dst, int n4) {
    int i = blockIdx.x * 256 + threadIdx.x;
    if (i < n4) {
        float4 v = ((const float4*)src)[i];
        ushort4 o;
        o.x = f2bf(v.x); o.y = f2bf(v.y); o.z = f2bf(v.z); o.w = f2bf(v.w);
        ((ushort4*)dst)[i] = o;
    }
}

__global__ __launch_bounds__(256) void k_rmsnorm(const float* __restrict__ x,
                                                 const float* __restrict__ ln_g,
                                                 ushort* __restrict__ xnb) {
    const int m = blockIdx.x;
    const int t = threadIdx.x;
    float4 v = ((const float4*)(x + (size_t)m * D_))[t];
    float ss = v.x * v.x + v.y * v.y + v.z * v.z + v.w * v.w;
    #pragma unroll
    for (int off = 32; off > 0; off >>= 1) ss += __shfl_down(ss, off, 64);
    __shared__ float red[4];
    if ((t & 63) == 0) red[t >> 6] = ss;
    __syncthreads();
    float tot = red[0] + red[1] + red[2] + red[3];
    float rms = sqrtf(tot * (1.0f / (float)D_));
    float scale = ln_g[0] / fmaxf(rms, 1e-5f);
    ushort4 o;
    o.x = f2bf(v.x * scale); o.y = f2bf(v.y * scale);
    o.z = f2bf(v.z * scale); o.w = f2bf(v.w * scale);
    ((ushort4*)(xnb + (size_t)m * D_))[t] = o;
}

// ---------------------------------------------------------------------------
// GEMM1 (128-tile core, proven 162 us): uv = silu(xn @ uv_w^T); epilogue
// splits into u (row-major), vT (transposed via LDS), q/k (affine+pos).
// ---------------------------------------------------------------------------
__global__ __launch_bounds__(256, 3) void k_gemm1(
    const ushort* __restrict__ xnb, const ushort* __restrict__ uvwb,
    const float* __restrict__ gamma, const float* __restrict__ beta,
    const float* __restrict__ pos,
    ushort* __restrict__ u, ushort* __restrict__ vT,
    ushort* __restrict__ qb, ushort* __restrict__ kb)
{
    __shared__ __align__(16) ushort lds[17408];  // 34KB: gemm 2x8192, transpose 128x136
    ushort* ldsA = lds;
    ushort* ldsB = lds + 8192;
    ZERO_ACC
    int mt, nt;
    tile_swizzle(mt, nt);
    const int m0 = mt * 128;
    const int n0 = nt * 128;
    gemm_core(xnb, uvwb, D_, D_, D_, m0, n0, ldsA, ldsB, acc);
    EPI_INDICES

    if (nt < 16) {           // u tiles, row-major bf16
        #pragma unroll
        for (int mi = 0; mi < 4; ++mi)
            #pragma unroll
            for (int ni = 0; ni < 4; ++ni) {
                const int col = n0 + wn + ni * 16 + l15;
                #pragma unroll
                for (int r = 0; r < 4; ++r) {
                    const int row = m0 + wm + mi * 16 + quad * 4 + r;
                    u[(size_t)row * E_ + col] = f2bf(silu(acc[mi][ni][r]));
                }
            }
    } else if (nt < 32) {    // v tiles -> write vT[b][e][s] via LDS transpose
        const int b   = m0 >> 11;            // m0 / S_
        const int s0  = m0 & (S_ - 1);
        const int ec0 = n0 - E_;             // e base in [0,E)
        __syncthreads();  // all waves done with gemm LDS
        #pragma unroll
        for (int mi = 0; mi < 4; ++mi)
            #pragma unroll
            for (int ni = 0; ni < 4; ++ni) {
                const int col = wn + ni * 16 + l15;        // e-local
                const int row = wm + mi * 16 + quad * 4;   // s-local
                #pragma unroll
                for (int r = 0; r < 4; r += 2) {
                    ushort2 pr;
                    pr.x = f2bf(silu(acc[mi][ni][r]));
                    pr.y = f2bf(silu(acc[mi][ni][r + 1]));
                    *(ushort2*)&lds[col * 136 + row + r] = pr;
                }
            }
        __syncthreads();
        ushort* vTb = vT + ((size_t)b * E_ + ec0) * S_ + s0;
        #pragma unroll
        for (int i = 0; i < 8; ++i) {
            const int lin = i * 256 + t;
            const int e  = lin >> 4;
            const int sb = (lin & 15) * 8;
            *(short8*)(vTb + (size_t)e * S_ + sb) = *(const short8*)&lds[e * 136 + sb];
        }
    } else {                 // qk tile (exactly SDIM=128 cols)
        #pragma unroll
        for (int mi = 0; mi < 4; ++mi)
            #pragma unroll
            for (int ni = 0; ni < 4; ++ni) {
                const int sd = wn + ni * 16 + l15;  // 0..127
                const float g0 = gamma[sd], g1 = gamma[SD_ + sd];
                const float be0 = beta[sd], be1 = beta[SD_ + sd];
                #pragma unroll
                for (int r = 0; r < 4; ++r) {
                    const int row = m0 + wm + mi * 16 + quad * 4 + r;
                    const int srow = row & (S_ - 1);
                    float s = silu(acc[mi][ni][r]);
                    const float p = pos[(size_t)srow * SD_ + sd];
                    qb[(size_t)row * SD_ + sd] = f2bf(s * g0 + be0 + p);
                    kb[(size_t)row * SD_ + sd] = f2bf(s * g1 + be1 + p);
                }
            }
    }
}

// ---------------------------------------------------------------------------
// scores (128-tile core, K=128: TLP beats deep pipeline here):
// kern = relu(q @ k^T / sqrt(SDIM))^2, bf16, batch group of 4
// ---------------------------------------------------------------------------
__global__ __launch_bounds__(256, 3) void k_scores(
    const ushort* __restrict__ qb, const ushort* __restrict__ kb,
    ushort* __restrict__ kern, int b_off)
{
    __shared__ __align__(16) ushort ldsA[128 * 64];
    __shared__ __align__(16) ushort ldsB[128 * 64];
    ZERO_ACC
    const int bz = blockIdx.z;
    const int b  = b_off + bz;
    int mt, nt;
    tile_swizzle(mt, nt);
    const int m0 = mt * 128;
    const int n0 = nt * 128;
    gemm_core(qb + (size_t)b * S_ * SD_, kb + (size_t)b * S_ * SD_,
              SD_, SD_, SD_, m0, n0, ldsA, ldsB, acc);
    EPI_INDICES
    ushort* ko = kern + (size_t)bz * S_ * S_;
    const float inv = 0.08838834764831845f;  // 1/sqrt(128)
    #pragma unroll
    for (int mi = 0; mi < 4; ++mi)
        #pragma unroll
        for (int ni = 0; ni < 4; ++ni) {
            const int col = n0 + wn + ni * 16 + l15;
            #pragma unroll
            for (int r = 0; r < 4; ++r) {
                const int row = m0 + wm + mi * 16 + quad * 4 + r;
                float s = fmaxf(acc[mi][ni][r] * inv, 0.0f);
                ko[(size_t)row * S_ + col] = f2bf(s * s);
            }
        }
}

// ---------------------------------------------------------------------------
// kv: kvu = u .* (kern @ v), bf16, batch group of 4 (256-tile v3)
// ---------------------------------------------------------------------------
__global__ __launch_bounds__(512, 2) void k_kv(
    const ushort* __restrict__ kern, const ushort* __restrict__ vT,
    const ushort* __restrict__ u, ushort* __restrict__ kvu, int b_off)
{
    __shared__ __align__(16) ushort lds[65536];   // 128 KiB static
    ZERO_ACC256
    const int bz = blockIdx.z;
    const int b  = b_off + bz;
    int mt, nt;
    tile_swizzle4(mt, nt);
    const int m0 = mt * 256, n0 = nt * 256;
    gemm256(kern + (size_t)bz * S_ * S_, vT + (size_t)b * E_ * S_,
            S_, S_, S_, m0, n0, lds, acc);
    EPI256
    #pragma unroll
    for (int mq = 0; mq < 2; ++mq)
    #pragma unroll
    for (int nq = 0; nq < 2; ++nq)
    #pragma unroll
    for (int mi = 0; mi < 4; ++mi)
    #pragma unroll
    for (int ni = 0; ni < 2; ++ni) {
        const int col = n0 + nq * 128 + wc * 32 + ni * 16 + l15;
        const int rb  = m0 + mq * 128 + wr * 64 + mi * 16 + quad * 4;
        #pragma unroll
        for (int r = 0; r < 4; ++r) {
            const size_t gi = (size_t)(b * S_ + rb + r) * E_ + col;
            float uval = bf2f(u[gi]);
            kvu[gi] = f2bf(uval * acc[mq][nq][mi][ni][r]);
        }
    }
}

// ---------------------------------------------------------------------------
// out: out = x * res_scale + kvu @ o_w^T  (fp32 out, 256-tile v3)
// ---------------------------------------------------------------------------
__global__ __launch_bounds__(512, 2) void k_out(
    const ushort* __restrict__ kvu, const ushort* __restrict__ owb,
    const float* __restrict__ x, const float* __restrict__ res_scale,
    float* __restrict__ out)
{
    __shared__ __align__(16) ushort lds[65536];   // 128 KiB static
    ZERO_ACC256
    int mt, nt;
    tile_swizzle4(mt, nt);
    const int m0 = mt * 256, n0 = nt * 256;
    gemm256(kvu, owb, E_, E_, E_, m0, n0, lds, acc);
    EPI256
    #pragma unroll
    for (int mq = 0; mq < 2; ++mq)
    #pragma unroll
    for (int nq = 0; nq < 2; ++nq)
    #pragma unroll
    for (int mi = 0; mi < 4; ++mi)
    #pragma unroll
    for (int ni = 0; ni < 2; ++ni) {
        const int col = n0 + nq * 128 + wc * 32 + ni * 16 + l15;
        const float rs = res_scale[col];
        const int rb = m0 + mq * 128 + wr * 64 + mi * 16 + quad * 4;
        #pragma unroll
        for (int r = 0; r < 4; ++r) {
            const size_t gi = (size_t)(rb + r) * D_ + col;
            out[gi] = x[gi] * rs + acc[mq][nq][mi][ni][r];
        }
    }
}

// ---------------------------------------------------------------------------
// Workspace layout (~236 MiB):
//   region0 33.55MB : xnb (rmsnorm->gemm1), then kern chunk (4 batches)
//   uvwb 8.91MB | owb 4.19MB | u 67.11MB | kvu 67.11MB | vT 67.11MB
//   qb 4.19MB | kb 4.19MB
// ---------------------------------------------------------------------------
extern "C" void kernel_launch(void* const* d_in, const int* in_sizes, int n_in,
                              void* d_out, int out_size, void* d_ws, size_t ws_size,
                              hipStream_t stream)
{
    const float* x         = (const float*)d_in[0];
    const float* pos       = (const float*)d_in[1];
    const float* ln_g      = (const float*)d_in[2];
    const float* uv_w      = (const float*)d_in[3];
    const float* gamma     = (const float*)d_in[4];
    const float* beta      = (const float*)d_in[5];
    const float* o_w       = (const float*)d_in[6];
    const float* res_scale = (const float*)d_in[7];
    float* out = (float*)d_out;

    char* p = (char*)d_ws;
    ushort* region0 = (ushort*)p; p += (size_t)M_ * D_ * 2;
    ushort* uvwb    = (ushort*)p; p += (size_t)NUV2 * D_ * 2;
    ushort* owb     = (ushort*)p; p += (size_t)D_ * E_ * 2;
    ushort* u       = (ushort*)p; p += (size_t)M_ * E_ * 2;
    ushort* kvu     = (ushort*)p; p += (size_t)M_ * E_ * 2;
    ushort* vT      = (ushort*)p; p += (size_t)M_ * E_ * 2;
    ushort* qb      = (ushort*)p; p += (size_t)M_ * SD_ * 2;
    ushort* kb      = (ushort*)p; p += (size_t)M_ * SD_ * 2;

    ushort* xnb  = region0;   // dead after k_gemm1
    ushort* kern = region0;   // 4-batch chunk

    k_cvt<<<(NUV * D_ / 4 + 255) / 256, 256, 0, stream>>>(uv_w, uvwb, NUV * D_ / 4);
    k_cvt<<<(D_ * E_ / 4 + 255) / 256, 256, 0, stream>>>(o_w, owb, D_ * E_ / 4);
    k_rmsnorm<<<M_, 256, 0, stream>>>(x, ln_g, xnb);
    k_gemm1<<<dim3(NUV / 128, M_ / 128), 256, 0, stream>>>(xnb, uvwb, gamma, beta, pos, u, vT, qb, kb);
    for (int g = 0; g < 2; ++g) {
        k_scores<<<dim3(S_ / 128, S_ / 128, 4), 256, 0, stream>>>(qb, kb, kern, g * 4);
        k_kv<<<dim3(E_ / 256, S_ / 256, 4), 512, 0, stream>>>(kern, vT, u, kvu, g * 4);
    }
    k_out<<<dim3(D_ / 256, M_ / 256), 512, 0, stream>>>(kvu, owb, x, res_scale, out);
}

// Round 6
// 520.030 us; speedup vs baseline: 1.0765x; 1.0765x over previous
//
#include <hip/hip_runtime.h>
#include <stdint.h>

#define B_   8
#define S_   2048
#define D_   1024
#define E_   2048
#define SD_  128
#define M_   (B_ * S_)        // 16384
#define NUV  (2 * E_ + SD_)   // 4224
#define NUV2 4352             // padded region kept for layout stability

typedef __attribute__((ext_vector_type(8))) short short8;
typedef __attribute__((ext_vector_type(4))) float floatx4;

typedef __attribute__((address_space(1))) void as1_void;
typedef __attribute__((address_space(3))) void as3_void;

__device__ __forceinline__ ushort f2bf(float f) {
    uint32_t u = __float_as_uint(f);
    uint32_t r = (u + 0x7fffu + ((u >> 16) & 1u)) >> 16;  // RNE
    return (ushort)r;
}
__device__ __forceinline__ float bf2f(ushort h) {
    return __uint_as_float(((uint32_t)h) << 16);
}
__device__ __forceinline__ float silu(float z) {
    return z * __builtin_amdgcn_rcpf(1.0f + __expf(-z));
}
__device__ __forceinline__ void gld_lds16(const ushort* g, ushort* l) {
    __builtin_amdgcn_global_load_lds((const as1_void*)g, (as3_void*)l, 16, 0, 0);
}

// ===========================================================================
// 128-tile machinery (proven 875 TF on gemm1 shape; 3 blocks/CU overlap)
// ===========================================================================

// Two-level supertile swizzle: 8 m-tiles x 4 n-tiles per supertile (32 blocks).
__device__ __forceinline__ void tile_swizzle(int& mt, int& nt) {
    const int gx  = gridDim.x;                 // n-tiles
    const int lin = blockIdx.y * gx + blockIdx.x;
    const int bandSz = gx * 8;
    const int band = lin / bandSz;
    const int rem  = lin - band * bandSz;
    const int full = gx >> 2;                  // # full 4-wide n-chunks
    const int sc   = rem >> 5;                 // /32
    if (sc < full) {
        const int r2 = rem & 31;
        mt = band * 8 + (r2 & 7);
        nt = sc * 4 + (r2 >> 3);
    } else {                                   // remainder chunk (gx%4 cols)
        const int r3 = rem - full * 32;
        mt = band * 8 + (r3 & 7);
        nt = full * 4 + (r3 >> 3);
    }
}

// C[128x128] tile of A[M,K] @ B[N,K]^T. 4 waves 2x2, wave tile 64x64 =
// 4x4 MFMA 16x16x32. BK=64, 32KB LDS. 2-barrier K-loop, global_load_lds
// width=16, XOR-swizzled LDS (key=row&7) -> 0 bank conflicts.
__device__ __forceinline__ void gemm_core(
    const ushort* __restrict__ A, const ushort* __restrict__ B,
    int lda, int ldb, int K, int m0, int n0,
    ushort* ldsA, ushort* ldsB, floatx4 acc[4][4])
{
    const int t    = threadIdx.x;
    const int lane = t & 63;
    const int l15  = lane & 15;
    const int quad = lane >> 4;
    const int wave = t >> 6;
    const int wm   = (wave >> 1) * 64;
    const int wn   = (wave & 1) * 64;
    const int key  = l15 & 7;

    const ushort* gA[4]; const ushort* gB[4];
    ushort* lA[4]; ushort* lB[4];
    #pragma unroll
    for (int i = 0; i < 4; ++i) {
        const int c   = t + i * 256;
        const int row = c >> 3;
        const int gkc = ((c & 7) ^ (row & 7)) * 8;
        gA[i] = A + (size_t)(m0 + row) * lda + gkc;
        gB[i] = B + (size_t)(n0 + row) * ldb + gkc;
        lA[i] = ldsA + c * 8;
        lB[i] = ldsB + c * 8;
    }

    for (int kk = 0; kk < K; kk += 64) {
        __syncthreads();
        #pragma unroll
        for (int i = 0; i < 4; ++i) gld_lds16(gA[i] + kk, lA[i]);
        #pragma unroll
        for (int i = 0; i < 4; ++i) gld_lds16(gB[i] + kk, lB[i]);
        __syncthreads();  // vmcnt(0) drain -> staged data visible

        #pragma unroll
        for (int s = 0; s < 2; ++s) {
            const int koff = ((s * 4 + quad) ^ key) * 8;
            short8 af[4], bfr[4];
            #pragma unroll
            for (int mi = 0; mi < 4; ++mi)
                af[mi] = *(const short8*)(ldsA + (wm + mi * 16 + l15) * 64 + koff);
            #pragma unroll
            for (int ni = 0; ni < 4; ++ni)
                bfr[ni] = *(const short8*)(ldsB + (wn + ni * 16 + l15) * 64 + koff);
            #pragma unroll
            for (int mi = 0; mi < 4; ++mi)
                #pragma unroll
                for (int ni = 0; ni < 4; ++ni)
                    acc[mi][ni] = __builtin_amdgcn_mfma_f32_16x16x32_bf16(
                        af[mi], bfr[ni], acc[mi][ni], 0, 0, 0);
        }
    }
}

#define EPI_INDICES \
    const int t = threadIdx.x; \
    const int lane = t & 63, l15 = lane & 15, quad = lane >> 4; \
    const int wave = t >> 6, wm = (wave >> 1) * 64, wn = (wave & 1) * 64; \
    (void)t;

#define ZERO_ACC \
    floatx4 acc[4][4]; \
    _Pragma("unroll") \
    for (int i = 0; i < 4; ++i) \
        _Pragma("unroll") \
        for (int j = 0; j < 4; ++j) \
            _Pragma("unroll") \
            for (int r = 0; r < 4; ++r) acc[i][j][r] = 0.0f;

// ===========================================================================
// 256-tile 4-phase machinery (v2.1: like v2 but WITHOUT the lgkmcnt(0)+
// sched_barrier pin between ds_reads and MFMA -> compiler emits fine-grained
// counted lgkmcnt, overlapping early MFMAs with remaining LDS reads.
// Cross-wave safety: every ds_read is consumed by an in-phase MFMA, so all
// reads complete before the trailing s_barrier; overwriting stages are
// issued only after that barrier. vmcnt ledger unchanged from v2.)
// ===========================================================================

__device__ __forceinline__ void tile_swizzle4(int& mt, int& nt) {
    const int gx  = gridDim.x;                 // n-tiles
    const int lin = blockIdx.y * gx + blockIdx.x;
    const int bandSz = gx * 4;
    const int band = lin / bandSz;
    const int rem  = lin - band * bandSz;
    const int full = gx >> 2;
    const int sc   = rem >> 4;
    if (sc < full) {
        const int r2 = rem & 15;
        mt = band * 4 + (r2 & 3);
        nt = sc * 4 + (r2 >> 2);
    } else {
        const int r3 = rem - full * 16;
        mt = band * 4 + (r3 & 3);
        nt = full * 4 + (r3 >> 2);
    }
}

#define STAGE_A(bufn, h, kk) { \
    gld_lds16(gA0 + (size_t)(h) * a128 + (kk), LA##bufn + (h) * 8192 + t * 8); \
    gld_lds16(gA1 + (size_t)(h) * a128 + (kk), LA##bufn + (h) * 8192 + t * 8 + 4096); }
#define STAGE_B(bufn, h, kk) { \
    gld_lds16(gB0 + (size_t)(h) * b128 + (kk), LB##bufn + (h) * 8192 + t * 8); \
    gld_lds16(gB1 + (size_t)(h) * b128 + (kk), LB##bufn + (h) * 8192 + t * 8 + 4096); }

#define PHA(bufn, STAGES) { \
    short8 af_[4][2]; \
    { const ushort* pa_ = LA##bufn + aoff; \
      const ushort* pb_ = LB##bufn + boff; \
      _Pragma("unroll") \
      for (int mi_ = 0; mi_ < 4; ++mi_) { \
          af_[mi_][0] = *(const short8*)(pa_ + mi_ * 1024 + koff0); \
          af_[mi_][1] = *(const short8*)(pa_ + mi_ * 1024 + koff1); } \
      _Pragma("unroll") \
      for (int nq_ = 0; nq_ < 2; ++nq_) \
      _Pragma("unroll") \
      for (int ni_ = 0; ni_ < 2; ++ni_) { \
          bfv[nq_][ni_][0] = *(const short8*)(pb_ + nq_ * 8192 + ni_ * 1024 + koff0); \
          bfv[nq_][ni_][1] = *(const short8*)(pb_ + nq_ * 8192 + ni_ * 1024 + koff1); } } \
    STAGES \
    __builtin_amdgcn_s_barrier(); \
    __builtin_amdgcn_s_setprio(1); \
    _Pragma("unroll") \
    for (int nq_ = 0; nq_ < 2; ++nq_) \
    _Pragma("unroll") \
    for (int mi_ = 0; mi_ < 4; ++mi_) \
    _Pragma("unroll") \
    for (int ni_ = 0; ni_ < 2; ++ni_) { \
        acc[0][nq_][mi_][ni_] = __builtin_amdgcn_mfma_f32_16x16x32_bf16( \
            af_[mi_][0], bfv[nq_][ni_][0], acc[0][nq_][mi_][ni_], 0, 0, 0); \
        acc[0][nq_][mi_][ni_] = __builtin_amdgcn_mfma_f32_16x16x32_bf16( \
            af_[mi_][1], bfv[nq_][ni_][1], acc[0][nq_][mi_][ni_], 0, 0, 0); } \
    __builtin_amdgcn_s_setprio(0); \
    __builtin_amdgcn_s_barrier(); }

#define PHB(bufn, STAGES, WAITC) { \
    short8 af_[4][2]; \
    { const ushort* pa_ = LA##bufn + 8192 + aoff; \
      _Pragma("unroll") \
      for (int mi_ = 0; mi_ < 4; ++mi_) { \
          af_[mi_][0] = *(const short8*)(pa_ + mi_ * 1024 + koff0); \
          af_[mi_][1] = *(const short8*)(pa_ + mi_ * 1024 + koff1); } } \
    STAGES \
    __builtin_amdgcn_s_barrier(); \
    __builtin_amdgcn_s_setprio(1); \
    _Pragma("unroll") \
    for (int nq_ = 0; nq_ < 2; ++nq_) \
    _Pragma("unroll") \
    for (int mi_ = 0; mi_ < 4; ++mi_) \
    _Pragma("unroll") \
    for (int ni_ = 0; ni_ < 2; ++ni_) { \
        acc[1][nq_][mi_][ni_] = __builtin_amdgcn_mfma_f32_16x16x32_bf16( \
            af_[mi_][0], bfv[nq_][ni_][0], acc[1][nq_][mi_][ni_], 0, 0, 0); \
        acc[1][nq_][mi_][ni_] = __builtin_amdgcn_mfma_f32_16x16x32_bf16( \
            af_[mi_][1], bfv[nq_][ni_][1], acc[1][nq_][mi_][ni_], 0, 0, 0); } \
    __builtin_amdgcn_s_setprio(0); \
    WAITC \
    __builtin_amdgcn_s_barrier(); }

__device__ __forceinline__ void gemm256(
    const ushort* __restrict__ A, const ushort* __restrict__ B,
    int lda, int ldb, int K, int m0, int n0,
    ushort* lds, floatx4 (&acc)[2][2][4][2])
{
    const int t    = threadIdx.x;
    const int lane = t & 63;
    const int l15  = lane & 15;
    const int quad = lane >> 4;
    const int w    = t >> 6;
    const int wr   = w >> 2;
    const int wc   = w & 3;
    const int key  = l15 & 7;
    const int aoff  = (wr * 64 + l15) * 64;
    const int boff  = (wc * 32 + l15) * 64;
    const int koff0 = (quad ^ key) * 8;
    const int koff1 = ((quad + 4) ^ key) * 8;

    ushort* const LA0 = lds;
    ushort* const LA1 = lds + 16384;
    ushort* const LB0 = lds + 32768;
    ushort* const LB1 = lds + 49152;

    const int r0 = t >> 3;
    const int k0 = ((t & 7) ^ (r0 & 7)) * 8;
    const ushort* gA0 = A + (size_t)(m0 + r0) * lda + k0;
    const ushort* gA1 = gA0 + (size_t)64 * lda;
    const ushort* gB0 = B + (size_t)(n0 + r0) * ldb + k0;
    const ushort* gB1 = gB0 + (size_t)64 * ldb;
    const size_t a128 = (size_t)128 * lda;
    const size_t b128 = (size_t)128 * ldb;

    short8 bfv[2][2][2];   // [nq][ni][kh], loaded in PHA, reused in PHB

    STAGE_A(0, 0, 0) STAGE_A(0, 1, 0) STAGE_B(0, 0, 0) STAGE_B(0, 1, 0)
    STAGE_A(1, 0, 64) STAGE_B(1, 0, 64) STAGE_B(1, 1, 64)
    asm volatile("s_waitcnt vmcnt(6)" ::: "memory");
    __builtin_amdgcn_s_barrier();

    const int nIter = K >> 7;                          // K-tile pairs
    #pragma unroll 1
    for (int i = 0; i < nIter; ++i) {
        const bool lastI = (i == nIter - 1);
        const int kb = i * 128;
        PHA(0, STAGE_A(1, 1, kb + 64))
        PHB(0, if (!lastI) { STAGE_A(0, 0, kb + 128) STAGE_B(0, 0, kb + 128) STAGE_B(0, 1, kb + 128) },
               if (!lastI) { asm volatile("s_waitcnt vmcnt(6)" ::: "memory"); }
               else        { asm volatile("s_waitcnt vmcnt(0)" ::: "memory"); })
        PHA(1, if (!lastI) { STAGE_A(0, 1, kb + 128) })
        PHB(1, if (!lastI) { STAGE_A(1, 0, kb + 192) STAGE_B(1, 0, kb + 192) STAGE_B(1, 1, kb + 192) },
               if (!lastI) { asm volatile("s_waitcnt vmcnt(6)" ::: "memory"); })
    }
}

#define ZERO_ACC256 \
    floatx4 acc[2][2][4][2]; \
    _Pragma("unroll") for (int zq_ = 0; zq_ < 2; ++zq_) \
    _Pragma("unroll") for (int zn_ = 0; zn_ < 2; ++zn_) \
    _Pragma("unroll") for (int zm_ = 0; zm_ < 4; ++zm_) \
    _Pragma("unroll") for (int zl_ = 0; zl_ < 2; ++zl_) \
    _Pragma("unroll") for (int zr_ = 0; zr_ < 4; ++zr_) \
        acc[zq_][zn_][zm_][zl_][zr_] = 0.0f;

#define EPI256 \
    const int t = threadIdx.x; \
    const int lane = t & 63, l15 = lane & 15, quad = lane >> 4; \
    const int w = t >> 6, wr = w >> 2, wc = w & 3; \
    (void)t; (void)lane;

// ---------------------------------------------------------------------------
// prep kernels
// ---------------------------------------------------------------------------
__global__ __launch_bounds__(256) void k_cvt(const float* __restrict__ src,
                                             ushort* __restrict__ dst, int n4) {
    int i = blockIdx.x * 256 + threadIdx.x;
    if (i < n4) {
        float4 v = ((const float4*)src)[i];
        ushort4 o;
        o.x = f2bf(v.x); o.y = f2bf(v.y); o.z = f2bf(v.z); o.w = f2bf(v.w);
        ((ushort4*)dst)[i] = o;
    }
}

__global__ __launch_bounds__(256) void k_rmsnorm(const float* __restrict__ x,
                                                 const float* __restrict__ ln_g,
                                                 ushort* __restrict__ xnb) {
    const int m = blockIdx.x;
    const int t = threadIdx.x;
    float4 v = ((const float4*)(x + (size_t)m * D_))[t];
    float ss = v.x * v.x + v.y * v.y + v.z * v.z + v.w * v.w;
    #pragma unroll
    for (int off = 32; off > 0; off >>= 1) ss += __shfl_down(ss, off, 64);
    __shared__ float red[4];
    if ((t & 63) == 0) red[t >> 6] = ss;
    __syncthreads();
    float tot = red[0] + red[1] + red[2] + red[3];
    float rms = sqrtf(tot * (1.0f / (float)D_));
    float scale = ln_g[0] / fmaxf(rms, 1e-5f);
    ushort4 o;
    o.x = f2bf(v.x * scale); o.y = f2bf(v.y * scale);
    o.z = f2bf(v.z * scale); o.w = f2bf(v.w * scale);
    ((ushort4*)(xnb + (size_t)m * D_))[t] = o;
}

// ---------------------------------------------------------------------------
// GEMM1 (128-tile core, proven 162 us): uv = silu(xn @ uv_w^T); epilogue
// splits into u (row-major), vT (transposed via LDS), q/k (affine+pos).
// ---------------------------------------------------------------------------
__global__ __launch_bounds__(256, 3) void k_gemm1(
    const ushort* __restrict__ xnb, const ushort* __restrict__ uvwb,
    const float* __restrict__ gamma, const float* __restrict__ beta,
    const float* __restrict__ pos,
    ushort* __restrict__ u, ushort* __restrict__ vT,
    ushort* __restrict__ qb, ushort* __restrict__ kb)
{
    __shared__ __align__(16) ushort lds[17408];  // 34KB: gemm 2x8192, transpose 128x136
    ushort* ldsA = lds;
    ushort* ldsB = lds + 8192;
    ZERO_ACC
    int mt, nt;
    tile_swizzle(mt, nt);
    const int m0 = mt * 128;
    const int n0 = nt * 128;
    gemm_core(xnb, uvwb, D_, D_, D_, m0, n0, ldsA, ldsB, acc);
    EPI_INDICES

    if (nt < 16) {           // u tiles, row-major bf16
        #pragma unroll
        for (int mi = 0; mi < 4; ++mi)
            #pragma unroll
            for (int ni = 0; ni < 4; ++ni) {
                const int col = n0 + wn + ni * 16 + l15;
                #pragma unroll
                for (int r = 0; r < 4; ++r) {
                    const int row = m0 + wm + mi * 16 + quad * 4 + r;
                    u[(size_t)row * E_ + col] = f2bf(silu(acc[mi][ni][r]));
                }
            }
    } else if (nt < 32) {    // v tiles -> write vT[b][e][s] via LDS transpose
        const int b   = m0 >> 11;            // m0 / S_
        const int s0  = m0 & (S_ - 1);
        const int ec0 = n0 - E_;             // e base in [0,E)
        __syncthreads();  // all waves done with gemm LDS
        #pragma unroll
        for (int mi = 0; mi < 4; ++mi)
            #pragma unroll
            for (int ni = 0; ni < 4; ++ni) {
                const int col = wn + ni * 16 + l15;        // e-local
                const int row = wm + mi * 16 + quad * 4;   // s-local
                #pragma unroll
                for (int r = 0; r < 4; r += 2) {
                    ushort2 pr;
                    pr.x = f2bf(silu(acc[mi][ni][r]));
                    pr.y = f2bf(silu(acc[mi][ni][r + 1]));
                    *(ushort2*)&lds[col * 136 + row + r] = pr;
                }
            }
        __syncthreads();
        ushort* vTb = vT + ((size_t)b * E_ + ec0) * S_ + s0;
        #pragma unroll
        for (int i = 0; i < 8; ++i) {
            const int lin = i * 256 + t;
            const int e  = lin >> 4;
            const int sb = (lin & 15) * 8;
            *(short8*)(vTb + (size_t)e * S_ + sb) = *(const short8*)&lds[e * 136 + sb];
        }
    } else {                 // qk tile (exactly SDIM=128 cols)
        #pragma unroll
        for (int mi = 0; mi < 4; ++mi)
            #pragma unroll
            for (int ni = 0; ni < 4; ++ni) {
                const int sd = wn + ni * 16 + l15;  // 0..127
                const float g0 = gamma[sd], g1 = gamma[SD_ + sd];
                const float be0 = beta[sd], be1 = beta[SD_ + sd];
                #pragma unroll
                for (int r = 0; r < 4; ++r) {
                    const int row = m0 + wm + mi * 16 + quad * 4 + r;
                    const int srow = row & (S_ - 1);
                    float s = silu(acc[mi][ni][r]);
                    const float p = pos[(size_t)srow * SD_ + sd];
                    qb[(size_t)row * SD_ + sd] = f2bf(s * g0 + be0 + p);
                    kb[(size_t)row * SD_ + sd] = f2bf(s * g1 + be1 + p);
                }
            }
    }
}

// ---------------------------------------------------------------------------
// scores: kern = relu(q @ k^T / sqrt(SDIM))^2, bf16, batch group of 4 (256-tile)
// ---------------------------------------------------------------------------
__global__ __launch_bounds__(512, 2) void k_scores(
    const ushort* __restrict__ qb, const ushort* __restrict__ kb,
    ushort* __restrict__ kern, int b_off)
{
    __shared__ __align__(16) ushort lds[65536];   // 128 KiB static
    ZERO_ACC256
    const int bz = blockIdx.z;
    const int b  = b_off + bz;
    int mt, nt;
    tile_swizzle4(mt, nt);
    const int m0 = mt * 256, n0 = nt * 256;
    gemm256(qb + (size_t)b * S_ * SD_, kb + (size_t)b * S_ * SD_,
            SD_, SD_, SD_, m0, n0, lds, acc);
    EPI256
    ushort* ko = kern + (size_t)bz * S_ * S_;
    const float inv = 0.08838834764831845f;  // 1/sqrt(128)
    #pragma unroll
    for (int mq = 0; mq < 2; ++mq)
    #pragma unroll
    for (int nq = 0; nq < 2; ++nq)
    #pragma unroll
    for (int mi = 0; mi < 4; ++mi)
    #pragma unroll
    for (int ni = 0; ni < 2; ++ni) {
        const int col = n0 + nq * 128 + wc * 32 + ni * 16 + l15;
        const int rb  = m0 + mq * 128 + wr * 64 + mi * 16 + quad * 4;
        #pragma unroll
        for (int r = 0; r < 4; ++r) {
            float s = fmaxf(acc[mq][nq][mi][ni][r] * inv, 0.0f);
            ko[(size_t)(rb + r) * S_ + col] = f2bf(s * s);
        }
    }
}

// ---------------------------------------------------------------------------
// kv: kvu = u .* (kern @ v), bf16, batch group of 4 (256-tile)
// ---------------------------------------------------------------------------
__global__ __launch_bounds__(512, 2) void k_kv(
    const ushort* __restrict__ kern, const ushort* __restrict__ vT,
    const ushort* __restrict__ u, ushort* __restrict__ kvu, int b_off)
{
    __shared__ __align__(16) ushort lds[65536];   // 128 KiB static
    ZERO_ACC256
    const int bz = blockIdx.z;
    const int b  = b_off + bz;
    int mt, nt;
    tile_swizzle4(mt, nt);
    const int m0 = mt * 256, n0 = nt * 256;
    gemm256(kern + (size_t)bz * S_ * S_, vT + (size_t)b * E_ * S_,
            S_, S_, S_, m0, n0, lds, acc);
    EPI256
    #pragma unroll
    for (int mq = 0; mq < 2; ++mq)
    #pragma unroll
    for (int nq = 0; nq < 2; ++nq)
    #pragma unroll
    for (int mi = 0; mi < 4; ++mi)
    #pragma unroll
    for (int ni = 0; ni < 2; ++ni) {
        const int col = n0 + nq * 128 + wc * 32 + ni * 16 + l15;
        const int rb  = m0 + mq * 128 + wr * 64 + mi * 16 + quad * 4;
        #pragma unroll
        for (int r = 0; r < 4; ++r) {
            const size_t gi = (size_t)(b * S_ + rb + r) * E_ + col;
            float uval = bf2f(u[gi]);
            kvu[gi] = f2bf(uval * acc[mq][nq][mi][ni][r]);
        }
    }
}

// ---------------------------------------------------------------------------
// out: out = x * res_scale + kvu @ o_w^T  (fp32 out, 256-tile)
// ---------------------------------------------------------------------------
__global__ __launch_bounds__(512, 2) void k_out(
    const ushort* __restrict__ kvu, const ushort* __restrict__ owb,
    const float* __restrict__ x, const float* __restrict__ res_scale,
    float* __restrict__ out)
{
    __shared__ __align__(16) ushort lds[65536];   // 128 KiB static
    ZERO_ACC256
    int mt, nt;
    tile_swizzle4(mt, nt);
    const int m0 = mt * 256, n0 = nt * 256;
    gemm256(kvu, owb, E_, E_, E_, m0, n0, lds, acc);
    EPI256
    #pragma unroll
    for (int mq = 0; mq < 2; ++mq)
    #pragma unroll
    for (int nq = 0; nq < 2; ++nq)
    #pragma unroll
    for (int mi = 0; mi < 4; ++mi)
    #pragma unroll
    for (int ni = 0; ni < 2; ++ni) {
        const int col = n0 + nq * 128 + wc * 32 + ni * 16 + l15;
        const float rs = res_scale[col];
        const int rb = m0 + mq * 128 + wr * 64 + mi * 16 + quad * 4;
        #pragma unroll
        for (int r = 0; r < 4; ++r) {
            const size_t gi = (size_t)(rb + r) * D_ + col;
            out[gi] = x[gi] * rs + acc[mq][nq][mi][ni][r];
        }
    }
}

// ---------------------------------------------------------------------------
// Workspace layout (~236 MiB):
//   region0 33.55MB : xnb (rmsnorm->gemm1), then kern chunk (4 batches)
//   uvwb 8.91MB | owb 4.19MB | u 67.11MB | kvu 67.11MB | vT 67.11MB
//   qb 4.19MB | kb 4.19MB
// ---------------------------------------------------------------------------
extern "C" void kernel_launch(void* const* d_in, const int* in_sizes, int n_in,
                              void* d_out, int out_size, void* d_ws, size_t ws_size,
                              hipStream_t stream)
{
    const float* x         = (const float*)d_in[0];
    const float* pos       = (const float*)d_in[1];
    const float* ln_g      = (const float*)d_in[2];
    const float* uv_w      = (const float*)d_in[3];
    const float* gamma     = (const float*)d_in[4];
    const float* beta      = (const float*)d_in[5];
    const float* o_w       = (const float*)d_in[6];
    const float* res_scale = (const float*)d_in[7];
    float* out = (float*)d_out;

    char* p = (char*)d_ws;
    ushort* region0 = (ushort*)p; p += (size_t)M_ * D_ * 2;
    ushort* uvwb    = (ushort*)p; p += (size_t)NUV2 * D_ * 2;
    ushort* owb     = (ushort*)p; p += (size_t)D_ * E_ * 2;
    ushort* u       = (ushort*)p; p += (size_t)M_ * E_ * 2;
    ushort* kvu     = (ushort*)p; p += (size_t)M_ * E_ * 2;
    ushort* vT      = (ushort*)p; p += (size_t)M_ * E_ * 2;
    ushort* qb      = (ushort*)p; p += (size_t)M_ * SD_ * 2;
    ushort* kb      = (ushort*)p; p += (size_t)M_ * SD_ * 2;

    ushort* xnb  = region0;   // dead after k_gemm1
    ushort* kern = region0;   // 4-batch chunk

    k_cvt<<<(NUV * D_ / 4 + 255) / 256, 256, 0, stream>>>(uv_w, uvwb, NUV * D_ / 4);
    k_cvt<<<(D_ * E_ / 4 + 255) / 256, 256, 0, stream>>>(o_w, owb, D_ * E_ / 4);
    k_rmsnorm<<<M_, 256, 0, stream>>>(x, ln_g, xnb);
    k_gemm1<<<dim3(NUV / 128, M_ / 128), 256, 0, stream>>>(xnb, uvwb, gamma, beta, pos, u, vT, qb, kb);
    for (int g = 0; g < 2; ++g) {
        k_scores<<<dim3(S_ / 256, S_ / 256, 4), 512, 0, stream>>>(qb, kb, kern, g * 4);
        k_kv<<<dim3(E_ / 256, S_ / 256, 4), 512, 0, stream>>>(kern, vT, u, kvu, g * 4);
    }
    k_out<<<dim3(D_ / 256, M_ / 256), 512, 0, stream>>>(kvu, owb, x, res_scale, out);
}